// Round 1
// baseline (299.322 us; speedup 1.0000x reference)
//
#include <hip/hip_runtime.h>
#include <cstdint>

#define N_ 32
#define H_ 56
#define W_ 56
#define C_ 256
#define HP 58
#define WP 58

// ---------------- kernel 1: pack weight sign bits + |k| partial sums --------
// grid = 36 blocks (idx = p*4 + j, p = kh*3+kw in [0,9), j = word in [0,4))
// block = 256 threads (co). Reads coalesced across co.
__global__ void pack_w(const float* __restrict__ k, uint64_t* __restrict__ kb,
                       float* __restrict__ palpha) {
    int idx = blockIdx.x;            // 0..35
    int p = idx >> 2, j = idx & 3;
    int co = threadIdx.x;
    uint64_t bits = 0;
    float s = 0.f;
    #pragma unroll 8
    for (int b = 0; b < 64; ++b) {
        int ci = j * 64 + b;
        float v = k[(p * 256 + ci) * 256 + co];
        bits |= (uint64_t)(v > 0.f) << b;
        s += fabsf(v);
    }
    kb[idx * 256 + co] = bits;       // layout: kb[idx][co] -> coalesced in k3
    palpha[idx * 256 + co] = s;
}

// ---------------- kernel 2: pack input sign bits + beta ---------------------
// grid = N_*HP blocks (one padded row), block = 256 = 4 waves.
// Each wave handles padded columns xc = wave, wave+4, ...
// Word w of a pixel = ballot over channels [64w, 64w+64). Border pixels: x=0
// -> sign bit 0 (sign(0) = -1 in the reference), beta contribution 0.
__global__ void pack_x(const float* __restrict__ x, uint64_t* __restrict__ xb,
                       float* __restrict__ beta) {
    int bi = blockIdx.x;             // n*HP + y (padded row)
    int n = bi / HP, y = bi % HP;
    int wave = threadIdx.x >> 6, lane = threadIdx.x & 63;
    for (int xc = wave; xc < WP; xc += 4) {
        bool inb = (y >= 1 && y <= H_ && xc >= 1 && xc <= W_);
        float v0 = 0.f, v1 = 0.f, v2 = 0.f, v3 = 0.f;
        if (inb) {
            const float* px = x + (((size_t)n * H_ + (y - 1)) * W_ + (xc - 1)) * C_;
            v0 = px[lane];
            v1 = px[64 + lane];
            v2 = px[128 + lane];
            v3 = px[192 + lane];
        }
        uint64_t m0 = __ballot(v0 > 0.f);
        uint64_t m1 = __ballot(v1 > 0.f);
        uint64_t m2 = __ballot(v2 > 0.f);
        uint64_t m3 = __ballot(v3 > 0.f);
        float s = fabsf(v0) + fabsf(v1) + fabsf(v2) + fabsf(v3);
        #pragma unroll
        for (int m = 32; m >= 1; m >>= 1) s += __shfl_xor(s, m, 64);
        size_t pix = (size_t)bi * WP + xc;
        if (lane < 4) {
            uint64_t mw = (lane == 0) ? m0 : (lane == 1) ? m1 : (lane == 2) ? m2 : m3;
            xb[pix * 4 + lane] = mw;
        }
        if (lane == 0) beta[pix] = s * (1.f / 256.f);
    }
}

// ---------------- kernel 3: binary conv via xor+popcount --------------------
// grid = N_*H_ blocks (one output row), block = 256 threads (thread = cout).
// LDS holds 3 padded input rows of packed bits (broadcast reads, conflict-free).
// Each thread keeps 28 output accumulators in registers and sweeps input
// columns once per 28-wide chunk: 6 ds_read_b128 per input column.
__global__ __launch_bounds__(256) void bconv(
        const uint64_t* __restrict__ xb, const float* __restrict__ beta,
        const uint64_t* __restrict__ kb, const float* __restrict__ palpha,
        const float* __restrict__ bias, float* __restrict__ out) {
    int bi = blockIdx.x;             // n*H_ + h
    int n = bi / H_, h = bi % H_;
    int co = threadIdx.x;

    __shared__ __align__(16) uint64_t xs[3 * WP * 4];  // [r][col][word], 5568 B
    __shared__ float brow[3 * WP];
    __shared__ float bS[W_];

    // stage packed bits for padded rows h..h+2 (contiguous in global)
    const uint64_t* xsrc = xb + (size_t)(n * HP + h) * WP * 4;
    for (int i = threadIdx.x; i < 3 * WP * 4; i += 256) xs[i] = xsrc[i];
    const float* bsrc = beta + (size_t)(n * HP + h) * WP;
    for (int i = threadIdx.x; i < 3 * WP; i += 256) brow[i] = bsrc[i];
    __syncthreads();

    // 3x3 window sums of beta (the avg_pool), one thread per output w
    if (threadIdx.x < W_) {
        float s = 0.f;
        #pragma unroll
        for (int r = 0; r < 3; ++r)
            #pragma unroll
            for (int d = 0; d < 3; ++d) s += brow[r * WP + threadIdx.x + d];
        bS[threadIdx.x] = s * (1.f / 9.f);
    }

    // per-thread weight bits (36 x uint64 = 72 VGPRs) + alpha + bias
    uint64_t kr[36];
    float asum = 0.f;
    #pragma unroll
    for (int i = 0; i < 36; ++i) kr[i] = kb[i * 256 + co];
    #pragma unroll
    for (int i = 0; i < 36; ++i) asum += palpha[i * 256 + co];
    float alpha = asum * (1.f / 2304.f);
    float bv = bias[co];
    __syncthreads();   // bS visible

    float* orow = out + (size_t)(n * H_ + h) * W_ * C_ + co;

    for (int chunk = 0; chunk < 2; ++chunk) {   // w in [w0, w0+28)
        int w0 = chunk * 28;
        uint32_t acc[28];
        #pragma unroll
        for (int i = 0; i < 28; ++i) acc[i] = 0;
        #pragma unroll
        for (int xi = 0; xi < 30; ++xi) {       // input columns w0..w0+29
            #pragma unroll
            for (int r = 0; r < 3; ++r) {
                const uint64_t* px = &xs[(r * WP + w0 + xi) * 4];
                uint64_t x0 = px[0], x1 = px[1], x2 = px[2], x3 = px[3];
                #pragma unroll
                for (int kw = 0; kw < 3; ++kw) {
                    int wl = xi - kw;           // compile-time after unroll
                    if (wl >= 0 && wl < 28) {
                        int ki = (r * 3 + kw) * 4;
                        acc[wl] += __popcll(x0 ^ kr[ki])     + __popcll(x1 ^ kr[ki + 1])
                                 + __popcll(x2 ^ kr[ki + 2]) + __popcll(x3 ^ kr[ki + 3]);
                    }
                }
            }
        }
        #pragma unroll
        for (int wl = 0; wl < 28; ++wl) {
            int w = w0 + wl;
            float conv = (float)(2304 - 2 * (int)acc[wl]);
            orow[(size_t)w * C_] = conv * bS[w] * alpha + bv;
        }
    }
}

extern "C" void kernel_launch(void* const* d_in, const int* in_sizes, int n_in,
                              void* d_out, int out_size, void* d_ws, size_t ws_size,
                              hipStream_t stream) {
    const float* x    = (const float*)d_in[0];
    const float* k    = (const float*)d_in[1];
    const float* bias = (const float*)d_in[2];
    float* out = (float*)d_out;

    char* ws = (char*)d_ws;
    uint64_t* kb     = (uint64_t*)(ws);             //  73,728 B
    float*    palpha = (float*)(ws + 73728);        //  36,864 B
    uint64_t* xb     = (uint64_t*)(ws + 110592);    // 3,444,736 B
    float*    beta   = (float*)(ws + 3555328);      //   430,592 B (total ~4 MB)

    pack_w<<<36, 256, 0, stream>>>(k, kb, palpha);
    pack_x<<<N_ * HP, 256, 0, stream>>>(x, xb, beta);
    bconv<<<N_ * H_, 256, 0, stream>>>(xb, beta, kb, palpha, bias, out);
}